// Round 6
// baseline (1835.909 us; speedup 1.0000x reference)
//
#include <hip/hip_runtime.h>
#include <hip/hip_bf16.h>

typedef unsigned short u16;
typedef unsigned int u32;
typedef __attribute__((ext_vector_type(8))) short bf16x8;   // 8 bf16 = 4 VGPRs
typedef __attribute__((ext_vector_type(4))) float f32x4;

#define MFMA16(A, B, C) __builtin_amdgcn_mfma_f32_16x16x32_bf16((A), (B), (C), 0, 0, 0)

// tanh(x) = 1 - 2/(e^{2x}+1); exp2-based, saturates correctly at +/-inf
static __device__ __forceinline__ float fast_tanh(float x) {
  float e = __builtin_amdgcn_exp2f(x * 2.8853900817779268f);  // e^(2x)
  return 1.0f - 2.0f * __builtin_amdgcn_rcpf(e + 1.0f);
}
static __device__ __forceinline__ u16 f2bf(float f) {  // RNE fp32->bf16 (scalar)
  unsigned u = __builtin_bit_cast(unsigned, f);
  u += 0x7fffu + ((u >> 16) & 1u);
  return (u16)(u >> 16);
}
static __device__ __forceinline__ float bf2f(u16 h) {
  unsigned u = ((unsigned)h) << 16;
  return __builtin_bit_cast(float, u);
}
static __device__ __forceinline__ float bf2f_lo(u32 w) {  // low bf16 of pair
  return __builtin_bit_cast(float, w << 16);
}
static __device__ __forceinline__ float bf2f_hi(u32 w) {  // high bf16 of pair
  return __builtin_bit_cast(float, w & 0xffff0000u);
}
// pack 2 fp32 -> packed bf16x2; .x = low u16
static __device__ __forceinline__ u32 pk2(float a, float b) {
  __hip_bfloat162 h = __float22bfloat162_rn(make_float2(a, b));
  union { __hip_bfloat162 h; u32 u; } cv;
  cv.h = h;
  return cv.u;
}

// Gather one MFMA weight fragment: lane (q,c) element j holds W[r0+j][col].
// Used as the A operand (A[m=col][k=r0+j] of W^T).
static __device__ __forceinline__ bf16x8 load_wfrag(const void* W, bool isbf,
                                                    int N, int r0, int col) {
  union { bf16x8 v; u16 s[8]; } u;
  if (isbf) {
    const u16* p = (const u16*)W;
#pragma unroll
    for (int j = 0; j < 8; ++j) u.s[j] = p[(r0 + j) * N + col];
  } else {
    const float* p = (const float*)W;
#pragma unroll
    for (int j = 0; j < 8; ++j) u.s[j] = f2bf(p[(r0 + j) * N + col]);
  }
  return u.v;
}
static __device__ __forceinline__ float ldb(const void* p, bool isbf, int i) {
  return isbf ? bf2f(((const u16*)p)[i]) : ((const float*)p)[i];
}

// ---------------------------------------------------------------------------
// Fused NeuralODE, transposed world: z^T = W^T @ h^T per GEMM.
// 256 threads = 4 waves, 4-way feature split (halves LDS read redundancy vs
// the 8-wave variant, which measured AT the ~112 B/cyc/CU LDS ceiling):
//   H2(=256)-outputs: wave w owns feats [64w,64w+64)   (4 m-tiles)
//   H (=128)-outputs: wave w owns feats [32w,32w+32)   (2 m-tiles)
//   OUT(=64)-outputs: wave w owns feats [16w,16w+16)   (1 m-tile)
// Batch tile 32 (2 n-tiles). ~288 VGPRs of weight A-frags per wave -> 1
// wave/SIMD (launch_bounds(256,1)), 1 block/CU, grid 256.
// NUMERICS NOTE (R5 lesson): GEMM1/2 biases MUST be in accumulator init, not
// epilogue-add — the reordering alone moved absmax 0.0078 -> 0.032 (FAIL).
// This version's per-element op sequence is bitwise-identical to R4's PASS.
// ---------------------------------------------------------------------------
__global__ __launch_bounds__(256, 1) void node_main(
    const void* __restrict__ xv, void* __restrict__ outv,
    const void* __restrict__ Wenc, const void* __restrict__ benc,
    const void* __restrict__ W1, const void* __restrict__ b1,
    const void* __restrict__ W2, const void* __restrict__ b2,
    const void* __restrict__ W3, const void* __restrict__ b3,
    const void* __restrict__ Wdec, const void* __restrict__ bdec) {
  constexpr int STR = 264;  // 256 + 8 pad (keeps 16B alignment of fragments)
  __shared__ __align__(16) u16 zb0[32 * STR];
  __shared__ __align__(16) u16 zb1[32 * STR];

  const int tid = threadIdx.x;
  const int w = tid >> 6, L = tid & 63;   // w in 0..3
  const int q = L >> 4, c = L & 15;
  const float dt = 0.05f;

  // ---- runtime dtype detection (uniform): bf16 -> low u16 of u32 words of
  // W_enc has bf16-exponent in [110,124] ~always; f32 -> ~6%.
  int cnt = 0;
  {
    const unsigned* wu = (const unsigned*)Wenc;
#pragma unroll 1
    for (int i = 0; i < 64; ++i) {
      unsigned e = (wu[i] >> 7) & 0xFFu;
      cnt += (e >= 110u && e <= 124u) ? 1 : 0;
    }
  }
  const bool isbf = (cnt >= 32);

  // ---- register/AGPR-resident weight A-frags (per-wave feature slice) ----
  bf16x8 wef[2][2], w1f[4][4], w2f[8][4], w3f[8][2], wdf[4];
#pragma unroll
  for (int kt = 0; kt < 2; ++kt)
#pragma unroll
    for (int mt = 0; mt < 2; ++mt)
      wef[kt][mt] = load_wfrag(Wenc, isbf, 128, kt * 32 + q * 8, 32 * w + mt * 16 + c);
#pragma unroll
  for (int kt = 0; kt < 4; ++kt)
#pragma unroll
    for (int mt = 0; mt < 4; ++mt)
      w1f[kt][mt] = load_wfrag(W1, isbf, 256, kt * 32 + q * 8, 64 * w + mt * 16 + c);
#pragma unroll
  for (int kt = 0; kt < 8; ++kt)
#pragma unroll
    for (int mt = 0; mt < 4; ++mt)
      w2f[kt][mt] = load_wfrag(W2, isbf, 256, kt * 32 + q * 8, 64 * w + mt * 16 + c);
#pragma unroll
  for (int kt = 0; kt < 8; ++kt)
#pragma unroll
    for (int mt = 0; mt < 2; ++mt)
      w3f[kt][mt] = load_wfrag(W3, isbf, 128, kt * 32 + q * 8, 32 * w + mt * 16 + c);
#pragma unroll
  for (int kt = 0; kt < 4; ++kt)
    wdf[kt] = load_wfrag(Wdec, isbf, 64, kt * 32 + q * 8, 16 * w + c);

  // ---- biases. b1/b2 stored packed (register diet), unpacked into the
  // accumulator INIT (exact bf16 values — same fp32 numbers as R4). ----
  u32 b1p[4][2], b2p[4][2];   // [mt][pair]: feats 64w+16mt+4q+{0,1} / {2,3}
#pragma unroll
  for (int mt = 0; mt < 4; ++mt) {
    int base = 64 * w + 16 * mt + 4 * q;
    b1p[mt][0] = pk2(ldb(b1, isbf, base + 0), ldb(b1, isbf, base + 1));
    b1p[mt][1] = pk2(ldb(b1, isbf, base + 2), ldb(b1, isbf, base + 3));
    b2p[mt][0] = pk2(ldb(b2, isbf, base + 0), ldb(b2, isbf, base + 1));
    b2p[mt][1] = pk2(ldb(b2, isbf, base + 2), ldb(b2, isbf, base + 3));
  }
  f32x4 bei[2], b3i[2], bdi;
#pragma unroll
  for (int mt = 0; mt < 2; ++mt)
#pragma unroll
    for (int i = 0; i < 4; ++i) {
      bei[mt][i] = ldb(benc, isbf, 32 * w + 16 * mt + 4 * q + i);
      b3i[mt][i] = ldb(b3, isbf, 32 * w + 16 * mt + 4 * q + i);
    }
#pragma unroll
  for (int i = 0; i < 4; ++i) bdi[i] = ldb(bdec, isbf, 16 * w + 4 * q + i);

  float h[2][2][4], r[2][2][4];  // state: [mt][nt][i], feats 32w+16mt+4q+i

  // One f-eval: htmp in P -> z1 in Q -> z2 in P -> k (regs) -> htmp' in Q.
  auto feval = [&](int j, u16* __restrict__ P, u16* __restrict__ Q)
      __attribute__((always_inline)) {
    // ---- GEMM1: z1 = tanh(W1^T @ htmp + b1), K=128, out 4mt x 2nt ----
    f32x4 acc[4][2];
#pragma unroll
    for (int mt = 0; mt < 4; ++mt) {
      f32x4 bi = (f32x4){bf2f_lo(b1p[mt][0]), bf2f_hi(b1p[mt][0]),
                         bf2f_lo(b1p[mt][1]), bf2f_hi(b1p[mt][1])};
      acc[mt][0] = bi;
      acc[mt][1] = bi;
    }
#pragma unroll
    for (int kt = 0; kt < 4; ++kt) {
      bf16x8 bb0 = *(const bf16x8*)(P + c * STR + kt * 32 + 8 * q);
      bf16x8 bb1 = *(const bf16x8*)(P + (16 + c) * STR + kt * 32 + 8 * q);
#pragma unroll
      for (int mt = 0; mt < 4; ++mt) {
        acc[mt][0] = MFMA16(w1f[kt][mt], bb0, acc[mt][0]);
        acc[mt][1] = MFMA16(w1f[kt][mt], bb1, acc[mt][1]);
      }
    }
#pragma unroll
    for (int mt = 0; mt < 4; ++mt)
#pragma unroll
      for (int nt = 0; nt < 2; ++nt) {
        float t0 = fast_tanh(acc[mt][nt][0]), t1 = fast_tanh(acc[mt][nt][1]);
        float t2 = fast_tanh(acc[mt][nt][2]), t3 = fast_tanh(acc[mt][nt][3]);
        uint2 v; v.x = pk2(t0, t1); v.y = pk2(t2, t3);
        *(uint2*)(Q + (nt * 16 + c) * STR + 64 * w + 16 * mt + 4 * q) = v;
      }
    __syncthreads();

    // ---- GEMM2: z2 = tanh(W2^T @ z1 + b2), K=256 ----
#pragma unroll
    for (int mt = 0; mt < 4; ++mt) {
      f32x4 bi = (f32x4){bf2f_lo(b2p[mt][0]), bf2f_hi(b2p[mt][0]),
                         bf2f_lo(b2p[mt][1]), bf2f_hi(b2p[mt][1])};
      acc[mt][0] = bi;
      acc[mt][1] = bi;
    }
#pragma unroll
    for (int kt = 0; kt < 8; ++kt) {
      bf16x8 bb0 = *(const bf16x8*)(Q + c * STR + kt * 32 + 8 * q);
      bf16x8 bb1 = *(const bf16x8*)(Q + (16 + c) * STR + kt * 32 + 8 * q);
#pragma unroll
      for (int mt = 0; mt < 4; ++mt) {
        acc[mt][0] = MFMA16(w2f[kt][mt], bb0, acc[mt][0]);
        acc[mt][1] = MFMA16(w2f[kt][mt], bb1, acc[mt][1]);
      }
    }
    // After the GEMM1 barrier no wave touches P until the barrier below, so
    // overwriting P here is race-free (no extra barrier needed).
#pragma unroll
    for (int mt = 0; mt < 4; ++mt)
#pragma unroll
      for (int nt = 0; nt < 2; ++nt) {
        float t0 = fast_tanh(acc[mt][nt][0]), t1 = fast_tanh(acc[mt][nt][1]);
        float t2 = fast_tanh(acc[mt][nt][2]), t3 = fast_tanh(acc[mt][nt][3]);
        uint2 v; v.x = pk2(t0, t1); v.y = pk2(t2, t3);
        *(uint2*)(P + (nt * 16 + c) * STR + 64 * w + 16 * mt + 4 * q) = v;
      }
    __syncthreads();

    // ---- GEMM3: k = W3^T @ z2 + b3, K=256, out 2mt x 2nt ----
    f32x4 ak[2][2];
#pragma unroll
    for (int mt = 0; mt < 2; ++mt) { ak[mt][0] = b3i[mt]; ak[mt][1] = b3i[mt]; }
#pragma unroll
    for (int kt = 0; kt < 8; ++kt) {
      bf16x8 bb0 = *(const bf16x8*)(P + c * STR + kt * 32 + 8 * q);
      bf16x8 bb1 = *(const bf16x8*)(P + (16 + c) * STR + kt * 32 + 8 * q);
#pragma unroll
      for (int mt = 0; mt < 2; ++mt) {
        ak[mt][0] = MFMA16(w3f[kt][mt], bb0, ak[mt][0]);
        ak[mt][1] = MFMA16(w3f[kt][mt], bb1, ak[mt][1]);
      }
    }

    // ---- RK4 bookkeeping + write next htmp to Q (j literal -> folds) ----
    const float wc = (j == 1 || j == 2) ? 2.f : 1.f;
    const float cc = (j == 2) ? dt : 0.5f * dt;
#pragma unroll
    for (int mt = 0; mt < 2; ++mt)
#pragma unroll
      for (int nt = 0; nt < 2; ++nt) {
        float ht[4];
#pragma unroll
        for (int i = 0; i < 4; ++i) {
          float kv = ak[mt][nt][i];
          float rv = (j == 0) ? kv : r[mt][nt][i] + wc * kv;
          r[mt][nt][i] = rv;
          if (j == 3) {
            h[mt][nt][i] += (dt / 6.f) * rv;
            ht[i] = h[mt][nt][i];
          } else {
            ht[i] = h[mt][nt][i] + cc * kv;
          }
        }
        uint2 v; v.x = pk2(ht[0], ht[1]); v.y = pk2(ht[2], ht[3]);
        *(uint2*)(Q + (nt * 16 + c) * STR + 32 * w + 16 * mt + 4 * q) = v;
      }
    __syncthreads();
  };

#pragma unroll 1
  for (int tile = blockIdx.x; tile < 2048; tile += 256) {
    const int row0 = tile * 32;

    // ---- encoder: h0 = tanh(Wenc^T @ x^T + benc) -> regs + zb0 ----
    f32x4 he[2][2];
#pragma unroll
    for (int mt = 0; mt < 2; ++mt) { he[mt][0] = bei[mt]; he[mt][1] = bei[mt]; }
#pragma unroll
    for (int kt = 0; kt < 2; ++kt)
#pragma unroll
      for (int nt = 0; nt < 2; ++nt) {
        bf16x8 a;
        const int off = (row0 + nt * 16 + c) * 64 + kt * 32 + q * 8;
        if (isbf) {
          a = *(const bf16x8*)((const u16*)xv + off);
        } else {
          union { bf16x8 v; u16 s[8]; } u;
          const float* p = (const float*)xv + off;
#pragma unroll
          for (int j = 0; j < 8; ++j) u.s[j] = f2bf(p[j]);
          a = u.v;
        }
#pragma unroll
        for (int mt = 0; mt < 2; ++mt)
          he[mt][nt] = MFMA16(wef[kt][mt], a, he[mt][nt]);
      }
#pragma unroll
    for (int mt = 0; mt < 2; ++mt)
#pragma unroll
      for (int nt = 0; nt < 2; ++nt) {
#pragma unroll
        for (int i = 0; i < 4; ++i) h[mt][nt][i] = fast_tanh(he[mt][nt][i]);
        uint2 v;
        v.x = pk2(h[mt][nt][0], h[mt][nt][1]);
        v.y = pk2(h[mt][nt][2], h[mt][nt][3]);
        *(uint2*)(zb0 + (nt * 16 + c) * STR + 32 * w + 16 * mt + 4 * q) = v;
      }
    __syncthreads();

#pragma unroll 1
    for (int s = 0; s < 20; ++s) {
      feval(0, zb0, zb1);
      feval(1, zb1, zb0);
      feval(2, zb0, zb1);
      feval(3, zb1, zb0);
    }

    // ---- decoder: out = Wdec^T @ hT + bdec, hT in zb0 (K=128) ----
    f32x4 ad[2];
    ad[0] = bdi; ad[1] = bdi;
#pragma unroll
    for (int kt = 0; kt < 4; ++kt) {
      bf16x8 bb0 = *(const bf16x8*)(zb0 + c * STR + kt * 32 + 8 * q);
      bf16x8 bb1 = *(const bf16x8*)(zb0 + (16 + c) * STR + kt * 32 + 8 * q);
      ad[0] = MFMA16(wdf[kt], bb0, ad[0]);
      ad[1] = MFMA16(wdf[kt], bb1, ad[1]);
    }
#pragma unroll
    for (int nt = 0; nt < 2; ++nt) {
      const int ob = row0 + nt * 16 + c;        // batch row
      const int of = 16 * w + 4 * q;            // feature col (4 contiguous)
      if (isbf) {
        uint2 v; v.x = pk2(ad[nt][0], ad[nt][1]); v.y = pk2(ad[nt][2], ad[nt][3]);
        *(uint2*)((u16*)outv + ob * 64 + of) = v;
      } else {
#pragma unroll
        for (int i = 0; i < 4; ++i) ((float*)outv)[ob * 64 + of + i] = ad[nt][i];
      }
    }
    __syncthreads();  // protect zb0 before next tile's encoder writes
  }
}

extern "C" void kernel_launch(void* const* d_in, const int* in_sizes, int n_in,
                              void* d_out, int out_size, void* d_ws, size_t ws_size,
                              hipStream_t stream) {
  (void)in_sizes; (void)n_in; (void)out_size; (void)d_ws; (void)ws_size;
  node_main<<<256, 256, 0, stream>>>(
      d_in[0], d_out,
      d_in[1], d_in[2],   // W_enc, b_enc
      d_in[3], d_in[4],   // W1, b1
      d_in[5], d_in[6],   // W2, b2
      d_in[7], d_in[8],   // W3, b3
      d_in[9], d_in[10]); // W_dec, b_dec
}